// Round 5
// baseline (314.959 us; speedup 1.0000x reference)
//
#include <hip/hip_runtime.h>
#include <hip/hip_bf16.h>

// Problem constants (B=2, T=2048, C=2048, NH=16, L=128)
#define B_   2
#define T_   2048
#define C_   2048
#define NH_  16
#define L_   128
#define NKQ  2176   // L_ + NH_*L_
#define MTOK 4096   // B_*T_
#define SCALE_ 0.08838834764831845f           // 1/sqrt(128)
#define SCALE2_ 0.12753785792696073f          // SCALE_ * log2(e)

typedef short short8 __attribute__((ext_vector_type(8)));
typedef float f32x4  __attribute__((ext_vector_type(4)));

// async global->LDS, 16B per lane; LDS base must be wave-uniform.
#define GLD16(gp, lp) __builtin_amdgcn_global_load_lds(                      \
    (const __attribute__((address_space(1))) void*)(gp),                     \
    (__attribute__((address_space(3))) void*)(lp), 16, 0, 0)

__device__ __forceinline__ unsigned short f2bf(float f) {
  union { float f; unsigned u; } x; x.f = f;
  unsigned r = x.u + 0x7fffu + ((x.u >> 16) & 1u);   // RNE
  return (unsigned short)(r >> 16);
}

// ---------------- merged prep: cvt + 3 weight transposes + bias concat ----------------
__global__ __launch_bounds__(256) void prep_all(
    const float* __restrict__ x, const float* __restrict__ W_lat,
    const float* __restrict__ W_d, const float* __restrict__ W_proj,
    const float* __restrict__ b_lat, const float* __restrict__ b_d,
    unsigned short* __restrict__ x_bf, unsigned short* __restrict__ BtCat,
    unsigned short* __restrict__ WprojT, float* __restrict__ biascat) {
  __shared__ float tile[32][33];
  int bid = blockIdx.x;
  const int tid = threadIdx.x;

  if (bid < 8192) {                       // x fp32 -> bf16, 4 elems/thread
    int i = bid * 1024 + tid * 4;
    float4 v = *(const float4*)(x + i);
    ushort4 o;
    o.x = f2bf(v.x); o.y = f2bf(v.y); o.z = f2bf(v.z); o.w = f2bf(v.w);
    *(ushort4*)(x_bf + i) = o;
    return;
  }
  bid -= 8192;

  const float* W; unsigned short* Wt; int K, N; float mul; int nbx;
  if (bid < 256) {                        // W_lat [C][L] -> BtCat[0:L][C]
    W = W_lat; Wt = BtCat; K = C_; N = L_; mul = 1.f; nbx = 4;
  } else if (bid < 256 + 4096) {          // W_d [C][2048] -> BtCat[L:][C], fold scale*log2e
    bid -= 256;
    W = W_d; Wt = BtCat + (size_t)L_ * C_; K = C_; N = NH_ * L_; mul = SCALE2_; nbx = 64;
  } else if (bid < 256 + 8192) {          // W_proj [2048][C] -> WprojT[C][2048]
    bid -= 256 + 4096;
    W = W_proj; Wt = WprojT; K = NH_ * L_; N = C_; mul = 1.f; nbx = 64;
  } else {                                // bias concat [b_lat | scale*log2e*b_d]
    int i = (bid - (256 + 8192)) * 256 + tid;
    if (i < L_) biascat[i] = b_lat[i];
    else if (i < NKQ) biascat[i] = b_d[i - L_] * SCALE2_;
    return;
  }

  const int bx = (bid % nbx) * 32, by = (bid / nbx) * 32;
  const int tx = tid & 31, ty = tid >> 5;
  #pragma unroll
  for (int i2 = 0; i2 < 4; i2++)
    tile[ty + i2 * 8][tx] = W[(size_t)(by + ty + i2 * 8) * N + bx + tx];
  __syncthreads();
  #pragma unroll
  for (int i2 = 0; i2 < 4; i2++)
    Wt[(size_t)(bx + ty + i2 * 8) * K + by + tx] = f2bf(tile[tx][ty + i2 * 8] * mul);
}

// ---- transpose latent cols of kq -> KlT[b][l][t] (bf16) ----
__global__ void transpose_lat(const unsigned short* __restrict__ kq,
                              unsigned short* __restrict__ KlT) {
  __shared__ unsigned short tile[32][33];
  int t0 = blockIdx.x * 32, l0 = blockIdx.y * 32, b = blockIdx.z;
  int tx = threadIdx.x, ty = threadIdx.y;
  #pragma unroll
  for (int i = 0; i < 4; i++)
    tile[ty + i * 8][tx] = kq[((size_t)b * T_ + t0 + ty + i * 8) * NKQ + l0 + tx];
  __syncthreads();
  #pragma unroll
  for (int i = 0; i < 4; i++)
    KlT[((size_t)b * L_ + l0 + ty + i * 8) * T_ + t0 + tx] = tile[tx][ty + i * 8];
}

// ---------------- bf16 MFMA GEMM:  C = A @ Bt^T + bias ----------------
// R7: 3-buffer counted-vmcnt pipeline (T4), raw s_barrier (no vmcnt(0) drain in
// the loop), chunk-XOR LDS swizzle (T2), setprio around MFMA (T5).
// BM=256, BN=128, BK=64, 512 threads (8 waves, 4M x 2N, per-wave 64x64 out).
// Invariants: at iter t, vmcnt(6) forces tile t's 6 loads complete (tile t+1's
// 6 stay in flight -> never drain); s_barrier+sched_barrier then orders all
// waves' tile-(t-1) reads before STAGE(t+2) overwrites buf (t-1)%3.
// Grids: GEMM1 16x17 (N=2176 exact), GEMM2 16x16 (perfect 256-CU fill).
__global__ __launch_bounds__(512) void gemm_bt_bias(
    const unsigned short* __restrict__ A,   // [M][K] bf16
    const unsigned short* __restrict__ Bt,  // [N][K] bf16
    const float* __restrict__ bias,         // [N]
    unsigned short* __restrict__ Cb,        // bf16 out (or null)
    float* __restrict__ Cf,                 // fp32 out (or null)
    int M, int N, int K) {
  __shared__ __align__(16) unsigned short As[3][256 * 64];  // 96KB, swizzled
  __shared__ __align__(16) unsigned short Bs[3][128 * 64];  // 48KB, swizzled
  const int tid  = threadIdx.x;
  const int wave = tid >> 6, lane = tid & 63;
  const int lcol = lane & 15, quad = lane >> 4;
  const int wm = wave >> 1, wn = wave & 1;
  const int m0 = blockIdx.x * 256, n0 = blockIdx.y * 128;
  const int arow = lane >> 3, achunk = lane & 7;  // staging: 8 rows x 8 chunks/issue

  f32x4 acc[4][4];
  #pragma unroll
  for (int i = 0; i < 4; i++)
    #pragma unroll
    for (int j = 0; j < 4; j++) acc[i][j] = (f32x4){0.f, 0.f, 0.f, 0.f};

  const int nk = K >> 6;  // BK=64

  // stage tile kt into buffer buf (pre-swizzled global source, linear LDS dest)
  auto STAGE = [&](int kt, int buf) {
    const int kc = kt << 6;
    #pragma unroll
    for (int u = 0; u < 4; u++) {          // A: 256 rows
      int r0 = (wave * 4 + u) * 8;
      int rg = r0 + arow;
      int cl = (achunk ^ (rg & 7)) * 8;
      GLD16(&A[(size_t)(m0 + rg) * K + kc + cl], &As[buf][r0 * 64]);
    }
    #pragma unroll
    for (int u = 0; u < 2; u++) {          // B: 128 rows
      int r0 = (wave * 2 + u) * 8;
      int rg = r0 + arow;
      int cl = (achunk ^ (rg & 7)) * 8;
      GLD16(&Bt[(size_t)(n0 + rg) * K + kc + cl], &Bs[buf][r0 * 64]);
    }
  };

  STAGE(0, 0);
  STAGE(1, 1);

  for (int kt = 0; kt < nk; ++kt) {
    const int buf = kt % 3;
    if (kt + 1 < nk) asm volatile("s_waitcnt vmcnt(6)" ::: "memory");
    else             asm volatile("s_waitcnt vmcnt(0)" ::: "memory");
    __builtin_amdgcn_s_barrier();
    __builtin_amdgcn_sched_barrier(0);
    if (kt + 2 < nk) STAGE(kt + 2, (kt + 2) % 3);

    short8 af[4][2], bfr[4][2];
    #pragma unroll
    for (int m = 0; m < 4; m++)
      #pragma unroll
      for (int ks = 0; ks < 2; ks++) {
        int row = wm * 64 + m * 16 + lcol;
        af[m][ks] = *(const short8*)&As[buf][row * 64 + (((ks * 4 + quad) ^ (lcol & 7)) * 8)];
      }
    #pragma unroll
    for (int n = 0; n < 4; n++)
      #pragma unroll
      for (int ks = 0; ks < 2; ks++) {
        int row = wn * 64 + n * 16 + lcol;
        bfr[n][ks] = *(const short8*)&Bs[buf][row * 64 + (((ks * 4 + quad) ^ (lcol & 7)) * 8)];
      }
    __builtin_amdgcn_s_setprio(1);
    #pragma unroll
    for (int ks = 0; ks < 2; ks++)
      #pragma unroll
      for (int m = 0; m < 4; m++)
        #pragma unroll
        for (int n = 0; n < 4; n++)
          acc[m][n] = __builtin_amdgcn_mfma_f32_16x16x32_bf16(af[m][ks], bfr[n][ks], acc[m][n], 0, 0, 0);
    __builtin_amdgcn_s_setprio(0);
  }

  #pragma unroll
  for (int m = 0; m < 4; m++) {
    #pragma unroll
    for (int n = 0; n < 4; n++) {
      int col = n0 + wn * 64 + n * 16 + lcol;
      float bv = bias[col];
      #pragma unroll
      for (int r = 0; r < 4; r++) {
        int row = m0 + wm * 64 + m * 16 + quad * 4 + r;
        float v = acc[m][n][r] + bv;
        if (Cf) Cf[(size_t)row * N + col] = v;
        else    Cb[(size_t)row * N + col] = f2bf(v);
      }
    }
  }
}

// ---------------- fused causal MLA attention (double-buffered K staging) ----------------
// Block: 4 waves = 4 heads, 32 q-rows. s-tiles of 64, K tiles double-buffered.
// Grid 512: n<256 heavy tile (63-qi), n>=256 light (qi) -> heavy+light pair per CU.
// No-max softmax; scale*log2e folded into q; exp via v_exp2.
// R5: softmax+PV split by s-halves; s_setprio(1) around MFMA clusters (T5).
__global__ __launch_bounds__(256, 2) void attn_mla(
    const unsigned short* __restrict__ kq,   // [B*T][NKQ]
    const unsigned short* __restrict__ KlT,  // [B][L][T]
    unsigned short* __restrict__ y) {        // [B*T][NH*L]
  __shared__ __align__(16) unsigned short Kr[2][64 * 128];   // [s][l] swizzled
  __shared__ __align__(16) unsigned short Kt[2][128 * 64];   // [l][s] swizzled
  __shared__ __align__(16) unsigned short Pls[4][32 * 64];   // per-wave P, swizzled

  const int tid  = threadIdx.x;
  const int wave = tid >> 6, lane = tid & 63;
  const int lcol = lane & 15, quad = lane >> 4;
  const int n    = blockIdx.x;
  const int slot = n >> 8, c = n & 255;
  const int hg   = c >> 5, qi = c & 31;
  const int b    = hg >> 2;
  const int h    = (hg & 3) * 4 + wave;
  const int qt32 = slot ? qi : (63 - qi);    // 32-row q-tile index
  const size_t rowbase = (size_t)b * T_;
  const int q0 = qt32 * 32;
  unsigned short* Pw = &Pls[wave][0];

  // Q fragments (A-layout m=lane&15, k=quad*8+j); scale*log2e pre-folded
  short8 qf[2][4];
  #pragma unroll
  for (int i = 0; i < 2; i++) {
    const unsigned short* qp = kq + (rowbase + q0 + i * 16 + lcol) * NKQ + L_ + h * L_;
    #pragma unroll
    for (int kc = 0; kc < 4; kc++)
      qf[i][kc] = *(const short8*)(qp + kc * 32 + quad * 8);
  }

  f32x4 acco[2][8];
  #pragma unroll
  for (int i = 0; i < 2; i++)
    #pragma unroll
    for (int ns = 0; ns < 8; ns++) acco[i][ns] = (f32x4){0.f, 0.f, 0.f, 0.f};
  float lsum[2][4];
  #pragma unroll
  for (int i = 0; i < 2; i++)
    #pragma unroll
    for (int r = 0; r < 4; r++) lsum[i][r] = 0.f;

  const int nt = (qt32 >> 1) + 1;

  // prologue: stage tile 0 into buffer 0 (swizzle computed per sub-load!)
  #pragma unroll
  for (int kk = 0; kk < 4; kk++) {
    int r0 = wave * 16 + kk * 4;
    int rg = r0 + (lane >> 4);
    int cl = ((lane & 15) ^ (rg & 7)) * 8;
    GLD16(kq + (rowbase + rg) * NKQ + cl, &Kr[0][r0 * 128]);
  }
  #pragma unroll
  for (int kk = 0; kk < 4; kk++) {
    int r0 = wave * 32 + kk * 8;
    int rg = r0 + (lane >> 3);
    int cl = ((lane & 7) ^ (rg & 7)) * 8;
    GLD16(KlT + ((size_t)b * L_ + rg) * T_ + cl, &Kt[0][r0 * 64]);
  }

  for (int ts = 0; ts < nt; ts++) {
    const int cur = ts & 1;
    __syncthreads();  // drains stage(ts) [issued one full phase ago] + guards buf reuse

    if (ts + 1 < nt) {  // prefetch next tile into the other buffer
      const int s1 = (ts + 1) * 64;
      #pragma unroll
      for (int kk = 0; kk < 4; kk++) {
        int r0 = wave * 16 + kk * 4;
        int rg = r0 + (lane >> 4);
        int cl = ((lane & 15) ^ (rg & 7)) * 8;
        GLD16(kq + (rowbase + s1 + rg) * NKQ + cl, &Kr[cur ^ 1][r0 * 128]);
      }
      #pragma unroll
      for (int kk = 0; kk < 4; kk++) {
        int r0 = wave * 32 + kk * 8;
        int rg = r0 + (lane >> 3);
        int cl = ((lane & 7) ^ (rg & 7)) * 8;
        GLD16(KlT + ((size_t)b * L_ + rg) * T_ + s1 + cl, &Kt[cur ^ 1][r0 * 64]);
      }
    }

    const unsigned short* Krc = &Kr[cur][0];
    const unsigned short* Ktc = &Kt[cur][0];

    // S(32x64) = Q @ K^T
    f32x4 accs[2][4];
    #pragma unroll
    for (int i = 0; i < 2; i++)
      #pragma unroll
      for (int ns = 0; ns < 4; ns++) accs[i][ns] = (f32x4){0.f, 0.f, 0.f, 0.f};
    __builtin_amdgcn_s_setprio(1);
    #pragma unroll
    for (int kc = 0; kc < 4; kc++)
      #pragma unroll
      for (int ns = 0; ns < 4; ns++) {
        short8 bfrag = *(const short8*)&Krc[(ns * 16 + lcol) * 128 +
                                            (((kc * 4 + quad) ^ (lcol & 7)) * 8)];
        #pragma unroll
        for (int i = 0; i < 2; i++)
          accs[i][ns] = __builtin_amdgcn_mfma_f32_16x16x32_bf16(qf[i][kc], bfrag, accs[i][ns], 0, 0, 0);
      }
    __builtin_amdgcn_s_setprio(0);

    // p = 2^s; truncate to bf16, lsum from truncated value. Split by s-halves.
    const bool diag = (ts == nt - 1);
    #pragma unroll
    for (int half = 0; half < 2; half++) {
      #pragma unroll
      for (int i = 0; i < 2; i++)
        #pragma unroll
        for (int n2 = 0; n2 < 2; n2++) {
          const int ns = half * 2 + n2;
          #pragma unroll
          for (int r = 0; r < 4; r++) {
            float v = accs[i][ns][r];
            int sg = ns * 16 + lcol;
            int qg = (qt32 & 1) * 32 + i * 16 + quad * 4 + r;
            if (diag && sg > qg) v = -1e30f;
            float e = __builtin_amdgcn_exp2f(v);
            unsigned eu = __float_as_uint(e) & 0xffff0000u;
            lsum[i][r] += __uint_as_float(eu);
            int row = i * 16 + quad * 4 + r;
            int col = ns * 16 + lcol;
            int phys = ((col >> 3) ^ (row & 7));
            Pw[row * 64 + phys * 8 + (col & 7)] = (unsigned short)(eu >> 16);
          }
        }

      // O(32x128) += P(32x[half]) @ K([half]x128)   (Pw wave-private: no barrier)
      short8 pa[2];
      #pragma unroll
      for (int i = 0; i < 2; i++)
        pa[i] = *(const short8*)&Pw[(i * 16 + lcol) * 64 +
                                    (((half * 4 + quad) ^ (lcol & 7)) * 8)];
      __builtin_amdgcn_s_setprio(1);
      #pragma unroll
      for (int ns = 0; ns < 8; ns++) {
        short8 bfrag = *(const short8*)&Ktc[(ns * 16 + lcol) * 64 +
                                            (((half * 4 + quad) ^ (lcol & 7)) * 8)];
        #pragma unroll
        for (int i = 0; i < 2; i++)
          acco[i][ns] = __builtin_amdgcn_mfma_f32_16x16x32_bf16(pa[i], bfrag, acco[i][ns], 0, 0, 0);
      }
      __builtin_amdgcn_s_setprio(0);
    }
  }

  // reduce row sums across the 16 lcol lanes (once)
  #pragma unroll
  for (int i = 0; i < 2; i++)
    #pragma unroll
    for (int r = 0; r < 4; r++) {
      float s = lsum[i][r];
      #pragma unroll
      for (int off = 1; off < 16; off <<= 1) s += __shfl_xor(s, off, 64);
      lsum[i][r] = 1.f / s;
    }

  // write y
  #pragma unroll
  for (int i = 0; i < 2; i++)
    #pragma unroll
    for (int ns = 0; ns < 8; ns++)
      #pragma unroll
      for (int r = 0; r < 4; r++) {
        int qg = q0 + i * 16 + quad * 4 + r;
        y[(rowbase + qg) * (NH_ * L_) + h * L_ + ns * 16 + lcol] =
            f2bf(acco[i][ns][r] * lsum[i][r]);
      }
}

extern "C" void kernel_launch(void* const* d_in, const int* in_sizes, int n_in,
                              void* d_out, int out_size, void* d_ws, size_t ws_size,
                              hipStream_t stream) {
  const float* x      = (const float*)d_in[0];
  const float* W_lat  = (const float*)d_in[1];
  const float* b_lat  = (const float*)d_in[2];
  const float* W_d    = (const float*)d_in[3];
  const float* b_d    = (const float*)d_in[4];
  const float* W_proj = (const float*)d_in[5];
  const float* b_proj = (const float*)d_in[6];
  float* out = (float*)d_out;

  // workspace layout (bf16 buffers, 16B aligned)
  unsigned short* x_bf   = (unsigned short*)d_ws;                  // [4096][2048]
  unsigned short* BtCat  = x_bf   + (size_t)MTOK * C_;             // [2176][2048]
  unsigned short* WprojT = BtCat  + (size_t)NKQ * C_;              // [2048][2048]
  unsigned short* kqbuf  = WprojT + (size_t)C_ * (NH_ * L_);       // [4096][2176]
  unsigned short* ybuf   = kqbuf  + (size_t)MTOK * NKQ;            // [4096][2048]
  unsigned short* KlT    = ybuf   + (size_t)MTOK * (NH_ * L_);     // [2][128][2048]
  float*          biascat = (float*)(KlT + (size_t)B_ * L_ * T_);  // [2176]

  // 1. merged prep: x->bf16, weight transposes (scale folded), bias concat
  prep_all<<<16649, 256, 0, stream>>>(x, W_lat, W_d, W_proj, b_lat, b_d,
                                      x_bf, BtCat, WprojT, biascat);
  // 2. kq = x @ [W_lat | scale*log2e*W_d] + bias (bf16 out)
  gemm_bt_bias<<<dim3(MTOK / 256, NKQ / 128), 512, 0, stream>>>(
      x_bf, BtCat, biascat, kqbuf, nullptr, MTOK, NKQ, C_);
  // 3. latent transpose for PV staging
  transpose_lat<<<dim3(T_ / 32, L_ / 32, B_), dim3(32, 8), 0, stream>>>(kqbuf, KlT);
  // 4. causal MLA attention (512 balanced blocks, double-buffered)
  attn_mla<<<512, 256, 0, stream>>>(kqbuf, KlT, ybuf);
  // 5. out = y @ W_proj + b_proj (fp32 out)
  gemm_bt_bias<<<dim3(MTOK / 256, C_ / 128), 512, 0, stream>>>(
      ybuf, WprojT, b_proj, nullptr, out, MTOK, C_, C_);
}

// Round 6
// 277.469 us; speedup vs baseline: 1.1351x; 1.1351x over previous
//
#include <hip/hip_runtime.h>
#include <hip/hip_bf16.h>

// Problem constants (B=2, T=2048, C=2048, NH=16, L=128)
#define B_   2
#define T_   2048
#define C_   2048
#define NH_  16
#define L_   128
#define NKQ  2176   // L_ + NH_*L_
#define MTOK 4096   // B_*T_
#define SCALE2_ 0.12753785792696073f          // (1/sqrt(128)) * log2(e)

typedef short short8 __attribute__((ext_vector_type(8)));
typedef float f32x4  __attribute__((ext_vector_type(4)));
typedef float f32x16 __attribute__((ext_vector_type(16)));

// async global->LDS, 16B per lane; LDS base must be wave-uniform.
#define GLD16(gp, lp) __builtin_amdgcn_global_load_lds(                      \
    (const __attribute__((address_space(1))) void*)(gp),                     \
    (__attribute__((address_space(3))) void*)(lp), 16, 0, 0)

__device__ __forceinline__ unsigned short f2bf(float f) {
  union { float f; unsigned u; } x; x.f = f;
  unsigned r = x.u + 0x7fffu + ((x.u >> 16) & 1u);   // RNE
  return (unsigned short)(r >> 16);
}

// ---------------- merged prep: cvt + 3 weight transposes + bias concat ----------------
__global__ __launch_bounds__(256) void prep_all(
    const float* __restrict__ x, const float* __restrict__ W_lat,
    const float* __restrict__ W_d, const float* __restrict__ W_proj,
    const float* __restrict__ b_lat, const float* __restrict__ b_d,
    unsigned short* __restrict__ x_bf, unsigned short* __restrict__ BtCat,
    unsigned short* __restrict__ WprojT, float* __restrict__ biascat) {
  __shared__ float tile[32][33];
  int bid = blockIdx.x;
  const int tid = threadIdx.x;

  if (bid < 8192) {                       // x fp32 -> bf16, 4 elems/thread
    int i = bid * 1024 + tid * 4;
    float4 v = *(const float4*)(x + i);
    ushort4 o;
    o.x = f2bf(v.x); o.y = f2bf(v.y); o.z = f2bf(v.z); o.w = f2bf(v.w);
    *(ushort4*)(x_bf + i) = o;
    return;
  }
  bid -= 8192;

  const float* W; unsigned short* Wt; int K, N; float mul; int nbx;
  if (bid < 256) {                        // W_lat [C][L] -> BtCat[0:L][C]
    W = W_lat; Wt = BtCat; K = C_; N = L_; mul = 1.f; nbx = 4;
  } else if (bid < 256 + 4096) {          // W_d [C][2048] -> BtCat[L:][C], fold scale*log2e
    bid -= 256;
    W = W_d; Wt = BtCat + (size_t)L_ * C_; K = C_; N = NH_ * L_; mul = SCALE2_; nbx = 64;
  } else if (bid < 256 + 8192) {          // W_proj [2048][C] -> WprojT[C][2048]
    bid -= 256 + 4096;
    W = W_proj; Wt = WprojT; K = NH_ * L_; N = C_; mul = 1.f; nbx = 64;
  } else {                                // bias concat [b_lat | scale*log2e*b_d]
    int i = (bid - (256 + 8192)) * 256 + tid;
    if (i < L_) biascat[i] = b_lat[i];
    else if (i < NKQ) biascat[i] = b_d[i - L_] * SCALE2_;
    return;
  }

  const int bx = (bid % nbx) * 32, by = (bid / nbx) * 32;
  const int tx = tid & 31, ty = tid >> 5;
  #pragma unroll
  for (int i2 = 0; i2 < 4; i2++)
    tile[ty + i2 * 8][tx] = W[(size_t)(by + ty + i2 * 8) * N + bx + tx];
  __syncthreads();
  #pragma unroll
  for (int i2 = 0; i2 < 4; i2++)
    Wt[(size_t)(bx + ty + i2 * 8) * K + by + tx] = f2bf(tile[tx][ty + i2 * 8] * mul);
}

// ---- transpose latent cols of kq -> KlT[b][l][t] (bf16) ----
__global__ void transpose_lat(const unsigned short* __restrict__ kq,
                              unsigned short* __restrict__ KlT) {
  __shared__ unsigned short tile[32][33];
  int t0 = blockIdx.x * 32, l0 = blockIdx.y * 32, b = blockIdx.z;
  int tx = threadIdx.x, ty = threadIdx.y;
  #pragma unroll
  for (int i = 0; i < 4; i++)
    tile[ty + i * 8][tx] = kq[((size_t)b * T_ + t0 + ty + i * 8) * NKQ + l0 + tx];
  __syncthreads();
  #pragma unroll
  for (int i = 0; i < 4; i++)
    KlT[((size_t)b * L_ + l0 + ty + i * 8) * T_ + t0 + tx] = tile[tx][ty + i * 8];
}

// ---------------- bf16 MFMA GEMM:  C = A @ Bt^T + bias ----------------
// R6 (measured 64us each): double-buffered LDS staging, 128x128 tile, BK=32.
// prologue stage(0); loop { barrier; stage(kt+1 -> buf^1); ds_read+MFMA(buf) }
// -> the loop-top barrier drains loads issued one full compute phase ago.
// R7's 3-buffer counted-vmcnt variant REGRESSED (92us, MfmaUtil 15%): the
// "memory"-clobbered asm waitcnt + sched_barrier(0) defeated compiler
// scheduling at 1 block/CU (m141-class). Reverted to this proven version.
__global__ __launch_bounds__(256) void gemm_bt_bias(
    const unsigned short* __restrict__ A,   // [M][K] bf16
    const unsigned short* __restrict__ Bt,  // [N][K] bf16
    const float* __restrict__ bias,         // [N]
    unsigned short* __restrict__ Cb,        // bf16 out (or null)
    float* __restrict__ Cf,                 // fp32 out (or null)
    int M, int N, int K) {
  __shared__ __align__(16) unsigned short As[2][128 * 32];  // dbuf, BK=32
  __shared__ __align__(16) unsigned short Bs[2][128 * 32];
  const int tid  = threadIdx.x;
  const int wave = tid >> 6, lane = tid & 63;
  const int lcol = lane & 15, quad = lane >> 4;
  const int m0 = blockIdx.x * 128, n0 = blockIdx.y * 128;
  const int wm = (wave >> 1) * 64, wn = (wave & 1) * 64;
  const int lrow = lane >> 2, lchunk = (lane & 3) * 8;
  const int rb = wave * 32;

  f32x4 acc[4][4];
  #pragma unroll
  for (int i = 0; i < 4; i++)
    #pragma unroll
    for (int j = 0; j < 4; j++) acc[i][j] = (f32x4){0.f, 0.f, 0.f, 0.f};

  const int nk = K >> 5;
  // prologue: stage k-tile 0 into buffer 0
  GLD16(&A [(size_t)(m0 + rb      + lrow) * K + lchunk], &As[0][ rb       * 32]);
  GLD16(&A [(size_t)(m0 + rb + 16 + lrow) * K + lchunk], &As[0][(rb + 16) * 32]);
  GLD16(&Bt[(size_t)(n0 + rb      + lrow) * K + lchunk], &Bs[0][ rb       * 32]);
  GLD16(&Bt[(size_t)(n0 + rb + 16 + lrow) * K + lchunk], &Bs[0][(rb + 16) * 32]);

  for (int kt = 0; kt < nk; ++kt) {
    const int cur = kt & 1;
    __syncthreads();  // drains stage(kt) [issued one compute-phase ago] + guards buf reuse

    if (kt + 1 < nk) {  // prefetch next k-tile into the other buffer
      const int kc = (kt + 1) << 5;
      GLD16(&A [(size_t)(m0 + rb      + lrow) * K + kc + lchunk], &As[cur ^ 1][ rb       * 32]);
      GLD16(&A [(size_t)(m0 + rb + 16 + lrow) * K + kc + lchunk], &As[cur ^ 1][(rb + 16) * 32]);
      GLD16(&Bt[(size_t)(n0 + rb      + lrow) * K + kc + lchunk], &Bs[cur ^ 1][ rb       * 32]);
      GLD16(&Bt[(size_t)(n0 + rb + 16 + lrow) * K + kc + lchunk], &Bs[cur ^ 1][(rb + 16) * 32]);
    }

    short8 af[4], bfr[4];
    #pragma unroll
    for (int i = 0; i < 4; i++)
      af[i] = *(const short8*)&As[cur][(wm + i * 16 + lcol) * 32 + quad * 8];
    #pragma unroll
    for (int j = 0; j < 4; j++)
      bfr[j] = *(const short8*)&Bs[cur][(wn + j * 16 + lcol) * 32 + quad * 8];
    #pragma unroll
    for (int i = 0; i < 4; i++)
      #pragma unroll
      for (int j = 0; j < 4; j++)
        acc[i][j] = __builtin_amdgcn_mfma_f32_16x16x32_bf16(af[i], bfr[j], acc[i][j], 0, 0, 0);
  }

  #pragma unroll
  for (int i = 0; i < 4; i++) {
    #pragma unroll
    for (int j = 0; j < 4; j++) {
      int col = n0 + wn + j * 16 + lcol;
      float bv = bias[col];
      #pragma unroll
      for (int r = 0; r < 4; r++) {
        int row = m0 + wm + i * 16 + quad * 4 + r;
        float v = acc[i][j][r] + bv;
        if (Cf) Cf[(size_t)row * N + col] = v;
        else    Cb[(size_t)row * N + col] = f2bf(v);
      }
    }
  }
}

// ---------------- fused causal MLA attention (R8: in-register softmax) ----------------
// Block: 4 waves = 4 heads, 32 q-rows. s-tiles of 64, K tiles double-buffered
// (stage(0); loop { barrier; stage(ts+1 -> other buf); compute(ts) }).
// R8 rewrite: the old P-matrix LDS round-trip (32 ds_write_b16 + 4 reads/iter)
// dominated the per-wave serial chain (~624 DS-issue cyc/iter, ~49% of kernel).
// Now: swapped QK^T via 32x32x16 MFMA -> S^T: each lane holds P for its own
// q = lane&31 (col), s in rows (reg&3)+8*(reg>>2)+4*(lane>>5). P->bf16 PV
// A-frags built IN REGISTERS: 16 v_cvt_pk_bf16_f32 + 8 v_permlane32_swap_b32
// per tile (frag for kc: j0-3 from half0-lane pack[t], j4-7 from half1-lane
// pack[t], t = 2*(kc&1)+half_target -> one swap yields both). lsum = per-lane
// scalar summed from the frag bf16s (bit-consistent with MFMA input) + one
// shfl_xor(32) merge. DS/iter: 68 -> 32 instr, zero LDS writes.
// Kr swizzle widened to 4-bit XOR, Kt gets row-bit3 XOR -> <=2-way conflicts
// for the new 32-row read patterns.
// Grid 512: n<256 heavy tile (63-qi), n>=256 light (qi) -> pair per CU.
__global__ __launch_bounds__(256, 2) void attn_mla(
    const unsigned short* __restrict__ kq,   // [B*T][NKQ]
    const unsigned short* __restrict__ KlT,  // [B][L][T]
    unsigned short* __restrict__ y) {        // [B*T][NH*L]
  __shared__ __align__(16) unsigned short Kr[2][64 * 128];   // [s][l] swizzled (4-bit XOR)
  __shared__ __align__(16) unsigned short Kt[2][128 * 64];   // [l][s] swizzled (3+1-bit XOR)
  __shared__ __align__(16) float ls[4][32];                  // per-wave 1/lsum exchange

  const int tid  = threadIdx.x;
  const int wave = tid >> 6, lane = tid & 63;
  const int l31 = lane & 31, hf = lane >> 5;
  const int n    = blockIdx.x;
  const int slot = n >> 8, c = n & 255;
  const int hg   = c >> 5, qi = c & 31;
  const int b    = hg >> 2;
  const int h    = (hg & 3) * 4 + wave;
  const int qt32 = slot ? qi : (63 - qi);    // 32-row q-tile index
  const size_t rowbase = (size_t)b * T_;
  const int q0 = qt32 * 32;

  // Q as B-frags for swapped QK^T (n = q = lane&31, k = kc*16 + hf*8 + j)
  short8 qf[8];
  {
    const unsigned short* qp =
        kq + (rowbase + q0 + l31) * NKQ + L_ + h * L_ + hf * 8;
    #pragma unroll
    for (int kc = 0; kc < 8; kc++)
      qf[kc] = *(const short8*)(qp + kc * 16);
  }

  f32x16 acco[4];   // O[32q][128l]: 4 n-blocks of 32; rows = reg-form, col = l31
  #pragma unroll
  for (int nb = 0; nb < 4; nb++)
    #pragma unroll
    for (int r = 0; r < 16; r++) acco[nb][r] = 0.f;
  float lsum = 0.f;

  const int nt = (qt32 >> 1) + 1;

  // prologue: stage tile 0 into buffer 0 (swizzle computed per sub-load!)
  #pragma unroll
  for (int kk = 0; kk < 4; kk++) {
    int r0 = wave * 16 + kk * 4;
    int rg = r0 + (lane >> 4);
    int cl = ((lane & 15) ^ (rg & 15)) * 8;
    GLD16(kq + (rowbase + rg) * NKQ + cl, &Kr[0][r0 * 128]);
  }
  #pragma unroll
  for (int kk = 0; kk < 4; kk++) {
    int r0 = wave * 32 + kk * 8;
    int rg = r0 + (lane >> 3);
    int cl = ((lane & 7) ^ (rg & 7) ^ (((rg >> 3) & 1) << 2)) * 8;
    GLD16(KlT + ((size_t)b * L_ + rg) * T_ + cl, &Kt[0][r0 * 64]);
  }

  for (int ts = 0; ts < nt; ts++) {
    const int cur = ts & 1;
    __syncthreads();  // drains stage(ts) [issued one full phase ago] + guards buf reuse

    if (ts + 1 < nt) {  // prefetch next tile into the other buffer
      const int s1 = (ts + 1) * 64;
      #pragma unroll
      for (int kk = 0; kk < 4; kk++) {
        int r0 = wave * 16 + kk * 4;
        int rg = r0 + (lane >> 4);
        int cl = ((lane & 15) ^ (rg & 15)) * 8;
        GLD16(kq + (rowbase + s1 + rg) * NKQ + cl, &Kr[cur ^ 1][r0 * 128]);
      }
      #pragma unroll
      for (int kk = 0; kk < 4; kk++) {
        int r0 = wave * 32 + kk * 8;
        int rg = r0 + (lane >> 3);
        int cl = ((lane & 7) ^ (rg & 7) ^ (((rg >> 3) & 1) << 2)) * 8;
        GLD16(KlT + ((size_t)b * L_ + rg) * T_ + s1 + cl, &Kt[cur ^ 1][r0 * 64]);
      }
    }

    const unsigned short* Krc = &Kr[cur][0];
    const unsigned short* Ktc = &Kt[cur][0];

    // S^T(64s x 32q) = K @ Q^T : A = K from Kr (m=s), B = Q regs (n=q)
    f32x16 accs[2];
    #pragma unroll
    for (int sb = 0; sb < 2; sb++)
      #pragma unroll
      for (int r = 0; r < 16; r++) accs[sb][r] = 0.f;
    __builtin_amdgcn_s_setprio(1);
    #pragma unroll
    for (int kc = 0; kc < 8; kc++)
      #pragma unroll
      for (int sb = 0; sb < 2; sb++) {
        short8 kf = *(const short8*)&Krc[(sb * 32 + l31) * 128 +
                                          (((2 * kc + hf) ^ (l31 & 15)) * 8)];
        accs[sb] = __builtin_amdgcn_mfma_f32_32x32x16_bf16(kf, qf[kc], accs[sb], 0, 0, 0);
      }
    __builtin_amdgcn_s_setprio(0);

    // mask + p = 2^s (log2e pre-folded into W_d)
    const bool diag = (ts == nt - 1);
    const int qg = (qt32 & 1) * 32 + l31;
    #pragma unroll
    for (int sb = 0; sb < 2; sb++)
      #pragma unroll
      for (int r = 0; r < 16; r++) {
        float v = accs[sb][r];
        int s64 = sb * 32 + (r & 3) + 8 * (r >> 2) + 4 * hf;
        if (diag && s64 > qg) v = -1e30f;
        accs[sb][r] = __builtin_amdgcn_exp2f(v);
      }

    // PV: per kc (s-chunk of 16): build A-frag in regs (cvt_pk + permlane32_swap),
    // then 4 V-frags from Kt and 4 MFMAs. No LDS for P.
    #pragma unroll
    for (int kc = 0; kc < 4; kc++) {
      const int sb = kc >> 1;
      const int t0 = (kc & 1) * 2;          // packs t0 (regs 4t0..) and t0+1
      unsigned w00, w01, w10, w11;
      asm("v_cvt_pk_bf16_f32 %0, %1, %2" : "=v"(w00)
          : "v"(accs[sb][4 * t0 + 0]), "v"(accs[sb][4 * t0 + 1]));
      asm("v_cvt_pk_bf16_f32 %0, %1, %2" : "=v"(w01)
          : "v"(accs[sb][4 * t0 + 2]), "v"(accs[sb][4 * t0 + 3]));
      asm("v_cvt_pk_bf16_f32 %0, %1, %2" : "=v"(w10)
          : "v"(accs[sb][4 * t0 + 4]), "v"(accs[sb][4 * t0 + 5]));
      asm("v_cvt_pk_bf16_f32 %0, %1, %2" : "=v"(w11)
          : "v"(accs[sb][4 * t0 + 6]), "v"(accs[sb][4 * t0 + 7]));
      // VDST.hi <-> VSRC.lo: w00' = {half0 pack[t0]}, w10' = {half1 pack[t]}
      asm volatile("v_permlane32_swap_b32 %0, %1" : "+v"(w00), "+v"(w10));
      asm volatile("v_permlane32_swap_b32 %0, %1" : "+v"(w01), "+v"(w11));
      union { short8 s; unsigned u[4]; } F;
      F.u[0] = w00; F.u[1] = w01; F.u[2] = w10; F.u[3] = w11;
      // lsum from the exact bf16 values fed to the MFMA (own q = l31)
      #pragma unroll
      for (int w = 0; w < 4; w++) {
        lsum += __uint_as_float(F.u[w] << 16);
        lsum += __uint_as_float(F.u[w] & 0xffff0000u);
      }
      __builtin_amdgcn_s_setprio(1);
      #pragma unroll
      for (int nb = 0; nb < 4; nb++) {
        int rowv = nb * 32 + l31;
        short8 vf = *(const short8*)&Ktc[rowv * 64 +
            (((2 * kc + hf) ^ (rowv & 7) ^ (((rowv >> 3) & 1) << 2)) * 8)];
        acco[nb] = __builtin_amdgcn_mfma_f32_32x32x16_bf16(F.s, vf, acco[nb], 0, 0, 0);
      }
      __builtin_amdgcn_s_setprio(0);
    }
  }

  // lsum: merge halves (own half covered s = {16kc + 8*hf + j}), invert, exchange
  lsum += __shfl_xor(lsum, 32, 64);
  if (lane < 32) ls[wave][l31] = 1.f / lsum;
  __syncthreads();
  f32x4 rv[4];
  #pragma unroll
  for (int t = 0; t < 4; t++)
    rv[t] = *(const f32x4*)&ls[wave][8 * t + 4 * hf];

  // write y: q = q0 + (r&3)+8*(r>>2)+4*hf (rows), l = nb*32 + l31 (cols)
  #pragma unroll
  for (int nb = 0; nb < 4; nb++)
    #pragma unroll
    for (int r = 0; r < 16; r++) {
      int q = q0 + (r & 3) + 8 * (r >> 2) + 4 * hf;
      int l = nb * 32 + l31;
      y[(rowbase + q) * (NH_ * L_) + h * L_ + l] =
          f2bf(acco[nb][r] * rv[r >> 2][r & 3]);
    }
}

extern "C" void kernel_launch(void* const* d_in, const int* in_sizes, int n_in,
                              void* d_out, int out_size, void* d_ws, size_t ws_size,
                              hipStream_t stream) {
  const float* x      = (const float*)d_in[0];
  const float* W_lat  = (const float*)d_in[1];
  const float* b_lat  = (const float*)d_in[2];
  const float* W_d    = (const float*)d_in[3];
  const float* b_d    = (const float*)d_in[4];
  const float* W_proj = (const float*)d_in[5];
  const float* b_proj = (const float*)d_in[6];
  float* out = (float*)d_out;

  // workspace layout (bf16 buffers, 16B aligned)
  unsigned short* x_bf   = (unsigned short*)d_ws;                  // [4096][2048]
  unsigned short* BtCat  = x_bf   + (size_t)MTOK * C_;             // [2176][2048]
  unsigned short* WprojT = BtCat  + (size_t)NKQ * C_;              // [2048][2048]
  unsigned short* kqbuf  = WprojT + (size_t)C_ * (NH_ * L_);       // [4096][2176]
  unsigned short* ybuf   = kqbuf  + (size_t)MTOK * NKQ;            // [4096][2048]
  unsigned short* KlT    = ybuf   + (size_t)MTOK * (NH_ * L_);     // [2][128][2048]
  float*          biascat = (float*)(KlT + (size_t)B_ * L_ * T_);  // [2176]

  // 1. merged prep: x->bf16, weight transposes (scale folded), bias concat
  prep_all<<<16649, 256, 0, stream>>>(x, W_lat, W_d, W_proj, b_lat, b_d,
                                      x_bf, BtCat, WprojT, biascat);
  // 2. kq = x @ [W_lat | scale*log2e*W_d] + bias (bf16 out)
  gemm_bt_bias<<<dim3(MTOK / 128, NKQ / 128), 256, 0, stream>>>(
      x_bf, BtCat, biascat, kqbuf, nullptr, MTOK, NKQ, C_);
  // 3. latent transpose for PV staging
  transpose_lat<<<dim3(T_ / 32, L_ / 32, B_), dim3(32, 8), 0, stream>>>(kqbuf, KlT);
  // 4. causal MLA attention (512 balanced blocks, in-register softmax)
  attn_mla<<<512, 256, 0, stream>>>(kqbuf, KlT, ybuf);
  // 5. out = y @ W_proj + b_proj (fp32 out)
  gemm_bt_bias<<<dim3(MTOK / 128, C_ / 128), 256, 0, stream>>>(
      ybuf, WprojT, b_proj, nullptr, out, MTOK, C_, C_);
}